// Round 3
// baseline (672.574 us; speedup 1.0000x reference)
//
#include <hip/hip_runtime.h>
#include <cstdint>

#define GEPS 1e-6f

typedef __attribute__((ext_vector_type(8))) short bf16x8;
typedef __attribute__((ext_vector_type(4))) float f32x4;

__device__ __forceinline__ unsigned short f2bf(float f) {
  unsigned int u = __float_as_uint(f);
  u += 0x7fffu + ((u >> 16) & 1u);
  return (unsigned short)(u >> 16);
}

// Branch-free erf-based exact GELU: A&S 7.1.26, |erf err| <= 1.5e-7.
__device__ __forceinline__ float fast_gelu(float h) {
  float z  = h * 0.70710678118654752f;
  float az = __builtin_fabsf(z);
  float t  = __builtin_amdgcn_rcpf(__builtin_fmaf(0.3275911f, az, 1.0f));
  float poly = t * __builtin_fmaf(t, __builtin_fmaf(t, __builtin_fmaf(t,
               __builtin_fmaf(t, 1.061405429f, -1.453152027f),
               1.421413741f), -0.284496736f), 0.254829592f);
  float e  = __builtin_amdgcn_exp2f(z * z * -1.44269504088896341f);
  float er = __builtin_fmaf(-poly, e, 1.0f);        // erf(|z|)
  er = __builtin_copysignf(er, z);
  float h5 = 0.5f * h;
  return __builtin_fmaf(h5, er, h5);                // 0.5h*(1+erf)
}

// Pack W1 [C=256][H=256] fp32 -> bf16 fragment-major for the B-operand of
// mfma_f32_16x16x32_bf16. Coalesced: thread (h) packs 8 consecutive k into
// one uint4 store (vs 8 scattered 2B stores before). Reads are coalesced
// across threads for each j.
__global__ void pack_w1(const float* __restrict__ W1, unsigned short* __restrict__ wt) {
  int h  = threadIdx.x;              // 0..255 (H)
  int k8 = blockIdx.x;               // 0..31, group of 8 consecutive k
  int kk = k8 >> 2, q = k8 & 3;
  int h_tile = h >> 4, tl = h & 15;
  unsigned short tmp[8];
  #pragma unroll
  for (int j = 0; j < 8; ++j)
    tmp[j] = f2bf(W1[(k8 * 8 + j) * 256 + h]);
  *(uint4*)&wt[(((h_tile << 3) + kk) << 9) + (q << 7) + (tl << 3)] = *(uint4*)tmp;
}

__global__ __launch_bounds__(256, 5) void gater_main(
    const float* __restrict__ x, const unsigned short* __restrict__ wt,
    const float* __restrict__ b1, const float* __restrict__ w2,
    const float* __restrict__ b2, const int* __restrict__ kp,
    float* __restrict__ y, float* __restrict__ scores, float* __restrict__ probs,
    float* __restrict__ bg_ws, float* __restrict__ sums,
    unsigned int* __restrict__ cnt, float* __restrict__ aux)
{
  // 32 KB exactly -> 5 blocks/CU. Rows XOR-swizzled (col8 ^= row&7); scratch
  // aliases the A tile, which is dead after the MFMA fragment loads.
  __shared__ short A_lds[64 * 256];
  float* const sc_lds = (float*)A_lds;           // [4*64]
  float* const p_lds  = (float*)A_lds + 256;     // [64]
  float* const bg_lds = (float*)A_lds + 320;     // [4*256]

  const int tid = threadIdx.x;
  const int wave = tid >> 6;
  const int tok0 = blockIdx.x * 64;     // flat token index (b*N + n)
  const int b = tok0 >> 12;             // N = 4096
  const int n0 = tok0 & 4095;
  const float* xblk = x + (size_t)tok0 * 256;
  const float* xt = xblk + tid * 4;     // this thread's column window

  // ---- stage x tile fp32 -> bf16 into LDS (swizzled rows) ----
  #pragma unroll
  for (int i = 0; i < 16; ++i) {
    int token = i * 4 + wave;
    const float4 v = *(const float4*)(xt + i * 1024);
    unsigned int lo = (unsigned int)f2bf(v.x) | ((unsigned int)f2bf(v.y) << 16);
    unsigned int hi = (unsigned int)f2bf(v.z) | ((unsigned int)f2bf(v.w) << 16);
    int idx = token * 256 + (((tid & 63) << 2) ^ ((token & 7) << 3));
    *(uint2*)&A_lds[idx] = make_uint2(lo, hi);
  }
  __syncthreads();

  const int lane = tid & 63, tl = lane & 15, q = lane >> 4;

  f32x4 acc[4][4];
  #pragma unroll
  for (int mi = 0; mi < 4; ++mi)
    #pragma unroll
    for (int ni = 0; ni < 4; ++ni)
      acc[mi][ni] = (f32x4){0.f, 0.f, 0.f, 0.f};

  const bf16x8* wtv = (const bf16x8*)wt;
  const int aswz = (tl & 7) << 3;
  #pragma unroll
  for (int kk = 0; kk < 8; ++kk) {
    bf16x8 a[4], bb[4];
    #pragma unroll
    for (int mi = 0; mi < 4; ++mi)
      a[mi] = *(const bf16x8*)&A_lds[(mi * 16 + tl) * 256 + ((kk * 32 + q * 8) ^ aswz)];
    #pragma unroll
    for (int ni = 0; ni < 4; ++ni)
      bb[ni] = wtv[((((wave << 2) + ni) << 3) + kk) * 64 + lane];
    #pragma unroll
    for (int mi = 0; mi < 4; ++mi)
      #pragma unroll
      for (int ni = 0; ni < 4; ++ni)
        acc[mi][ni] = __builtin_amdgcn_mfma_f32_16x16x32_bf16(a[mi], bb[ni], acc[mi][ni], 0, 0, 0);
  }
  __syncthreads();   // all A_lds reads done -> safe to alias scratch into it

  // ---- epilogue: gelu(h + b1) . w2, reduce over this wave's 64 H cols ----
  float w2v[4], b1v[4];
  #pragma unroll
  for (int ni = 0; ni < 4; ++ni) {
    int h = wave * 64 + ni * 16 + tl;
    w2v[ni] = w2[h];
    b1v[ni] = b1[h];
  }
  #pragma unroll
  for (int mi = 0; mi < 4; ++mi) {
    #pragma unroll
    for (int r = 0; r < 4; ++r) {
      float s = 0.f;
      #pragma unroll
      for (int ni = 0; ni < 4; ++ni) {
        float hv = acc[mi][ni][r] + b1v[ni];
        s += fast_gelu(hv) * w2v[ni];
      }
      #pragma unroll
      for (int m = 1; m < 16; m <<= 1) s += __shfl_xor(s, m, 64);
      if (tl == 0) sc_lds[wave * 64 + mi * 16 + q * 4 + r] = s;
    }
  }
  __syncthreads();

  if (tid < 64) {
    float s = sc_lds[tid] + sc_lds[64 + tid] + sc_lds[128 + tid] + sc_lds[192 + tid] + b2[0];
    float e = __builtin_amdgcn_exp2f(s * -1.44269504088896341f);
    float p = __builtin_amdgcn_rcpf(1.0f + e);
    size_t g = (size_t)tok0 + tid;
    scores[g] = s;
    probs[g] = p;
    p_lds[tid] = p;
    float ent = -(p * logf(p + GEPS) + (1.0f - p) * logf(1.0f - p + GEPS));
    float sp = p, se = ent;
    #pragma unroll
    for (int m = 1; m < 64; m <<= 1) {
      sp += __shfl_xor(sp, m, 64);
      se += __shfl_xor(se, m, 64);
    }
    if (tid == 0) {
      atomicAdd(&sums[b * 2 + 0], sp);
      atomicAdd(&sums[b * 2 + 1], se);
    }
  }
  __syncthreads();

  // ---- y = x * p (L3-hot re-read of x) + bg partial accumulation ----
  float* const yt = y + ((size_t)b * 4097 + n0) * 256 + tid * 4;
  float4 bg = make_float4(0.f, 0.f, 0.f, 0.f);
  #pragma unroll
  for (int i = 0; i < 16; ++i) {
    float4 xv = *(const float4*)(xt + i * 1024);
    float p = p_lds[i * 4 + wave];
    float4 yv = make_float4(xv.x * p, xv.y * p, xv.z * p, xv.w * p);
    *(float4*)(yt + i * 1024) = yv;     // cached store (nt was a 2.5x WRITE_SIZE regression)
    float bw = 1.0f - p;
    bg.x += xv.x * bw; bg.y += xv.y * bw; bg.z += xv.z * bw; bg.w += xv.w * bw;
  }
  *(float4*)&bg_lds[tid * 4] = bg;
  __syncthreads();
  {
    float v = bg_lds[tid] + bg_lds[256 + tid] + bg_lds[512 + tid] + bg_lds[768 + tid];
    atomicAdd(&bg_ws[b * 256 + tid], v);
  }

  // ---- fused finalize: last block of each batch writes the bg row ----
  __threadfence();                       // order this thread's atomics device-wide
  __syncthreads();                       // all threads fenced; bg_lds reads done
  int* const flag = (int*)sc_lds;        // A_lds reuse (safe after barrier)
  float* const spb = (float*)sc_lds + 1;
  if (tid == 0) {
    unsigned int old = atomicAdd(&cnt[b], 1u);
    int last = (old == 63u);
    flag[0] = last;
    // coherent read via RMW: immune to per-XCD L2 staleness
    if (last) spb[0] = atomicAdd(&sums[b * 2 + 0], 0.0f);
  }
  __syncthreads();
  if (flag[0]) {
    float denom = fmaxf(4096.0f - spb[0], GEPS);
    float v = atomicAdd(&bg_ws[b * 256 + tid], 0.0f);
    y[((size_t)b * 4097 + 4096) * 256 + tid] = v / denom;
    if (tid == 0) {
      unsigned int oldb = atomicAdd(&cnt[32], 1u);
      if (oldb == 31u) {                 // globally last batch -> aux loss
        float t = (float)kp[0] / 4096.0f;
        float lr = 0.f, le = 0.f;
        for (int i = 0; i < 32; ++i) {
          float r = atomicAdd(&sums[i * 2 + 0], 0.0f) / 4096.0f;
          lr += (r - t) * (r - t);
          le += atomicAdd(&sums[i * 2 + 1], 0.0f);
        }
        aux[0] = lr / 32.0f + 0.01f * (le / (32.0f * 4096.0f));
      }
    }
  }
}

extern "C" void kernel_launch(void* const* d_in, const int* in_sizes, int n_in,
                              void* d_out, int out_size, void* d_ws, size_t ws_size,
                              hipStream_t stream) {
  const float* x  = (const float*)d_in[0];
  const float* W1 = (const float*)d_in[1];
  const float* b1 = (const float*)d_in[2];
  const float* w2 = (const float*)d_in[3];
  const float* b2 = (const float*)d_in[4];
  const int*   kp = (const int*)d_in[5];

  float* y = (float*)d_out;
  const size_t Y_ELEMS = (size_t)32 * 4097 * 256;   // 33,562,624
  float* aux    = y + Y_ELEMS;
  float* scores = aux + 1;
  float* probs  = scores + (size_t)32 * 4096;

  unsigned short* wt = (unsigned short*)d_ws;                 // 128 KB bf16 frag-major W1
  float* bg_ws = (float*)((char*)d_ws + 131072);              // 32x256 fp32
  float* sums  = bg_ws + 32 * 256;                            // 32 x {sum_p, sum_ent}
  unsigned int* cnt = (unsigned int*)(sums + 64);             // 32 per-batch + 1 global

  hipMemsetAsync(bg_ws, 0, (32 * 256 + 64 + 64) * sizeof(float), stream);
  pack_w1<<<32, 256, 0, stream>>>(W1, wt);
  gater_main<<<2048, 256, 0, stream>>>(x, wt, b1, w2, b2, kp,
                                       y, scores, probs, bg_ws, sums, cnt, aux);
}

// Round 4
// 344.484 us; speedup vs baseline: 1.9524x; 1.9524x over previous
//
#include <hip/hip_runtime.h>
#include <cstdint>

#define GEPS 1e-6f

typedef __attribute__((ext_vector_type(8))) short bf16x8;
typedef __attribute__((ext_vector_type(4))) float f32x4;

__device__ __forceinline__ unsigned short f2bf(float f) {
  unsigned int u = __float_as_uint(f);
  u += 0x7fffu + ((u >> 16) & 1u);
  return (unsigned short)(u >> 16);
}

// Branch-free erf-based exact GELU: A&S 7.1.26, |erf err| <= 1.5e-7.
__device__ __forceinline__ float fast_gelu(float h) {
  float z  = h * 0.70710678118654752f;
  float az = __builtin_fabsf(z);
  float t  = __builtin_amdgcn_rcpf(__builtin_fmaf(0.3275911f, az, 1.0f));
  float poly = t * __builtin_fmaf(t, __builtin_fmaf(t, __builtin_fmaf(t,
               __builtin_fmaf(t, 1.061405429f, -1.453152027f),
               1.421413741f), -0.284496736f), 0.254829592f);
  float e  = __builtin_amdgcn_exp2f(z * z * -1.44269504088896341f);
  float er = __builtin_fmaf(-poly, e, 1.0f);        // erf(|z|)
  er = __builtin_copysignf(er, z);
  float h5 = 0.5f * h;
  return __builtin_fmaf(h5, er, h5);                // 0.5h*(1+erf)
}

// Pack W1 [C=256][H=256] fp32 -> bf16 fragment-major for the B-operand of
// mfma_f32_16x16x32_bf16. Coalesced: thread (h) packs 8 consecutive k into
// one uint4 store.
__global__ void pack_w1(const float* __restrict__ W1, unsigned short* __restrict__ wt) {
  int h  = threadIdx.x;              // 0..255 (H)
  int k8 = blockIdx.x;               // 0..31, group of 8 consecutive k
  int kk = k8 >> 2, q = k8 & 3;
  int h_tile = h >> 4, tl = h & 15;
  unsigned short tmp[8];
  #pragma unroll
  for (int j = 0; j < 8; ++j)
    tmp[j] = f2bf(W1[(k8 * 8 + j) * 256 + h]);
  *(uint4*)&wt[(((h_tile << 3) + kk) << 9) + (q << 7) + (tl << 3)] = *(uint4*)tmp;
}

__global__ __launch_bounds__(256, 5) void gater_main(
    const float* __restrict__ x, const unsigned short* __restrict__ wt,
    const float* __restrict__ b1, const float* __restrict__ w2,
    const float* __restrict__ b2,
    float* __restrict__ y, float* __restrict__ scores, float* __restrict__ probs,
    float* __restrict__ bg_ws, float* __restrict__ sums)
{
  // 32 KB exactly -> 5 blocks/CU. Rows XOR-swizzled (col8 ^= row&7); scratch
  // aliases the A tile, which is dead after the MFMA fragment loads.
  // NOTE: no device-scope fences anywhere — __threadfence() on gfx950 forces
  // an L2 writeback per block (R3: +330 us). Cross-block reduction goes
  // through atomics consumed by a separate finalize kernel.
  __shared__ short A_lds[64 * 256];
  float* const sc_lds = (float*)A_lds;           // [4*64]
  float* const p_lds  = (float*)A_lds + 256;     // [64]
  float* const bg_lds = (float*)A_lds + 320;     // [4*256]

  const int tid = threadIdx.x;
  const int wave = tid >> 6;
  const int tok0 = blockIdx.x * 64;     // flat token index (b*N + n)
  const int b = tok0 >> 12;             // N = 4096
  const int n0 = tok0 & 4095;
  const float* xblk = x + (size_t)tok0 * 256;
  const float* xt = xblk + tid * 4;     // this thread's column window

  // ---- stage x tile fp32 -> bf16 into LDS (swizzled rows) ----
  #pragma unroll
  for (int i = 0; i < 16; ++i) {
    int token = i * 4 + wave;
    const float4 v = *(const float4*)(xt + i * 1024);
    unsigned int lo = (unsigned int)f2bf(v.x) | ((unsigned int)f2bf(v.y) << 16);
    unsigned int hi = (unsigned int)f2bf(v.z) | ((unsigned int)f2bf(v.w) << 16);
    int idx = token * 256 + (((tid & 63) << 2) ^ ((token & 7) << 3));
    *(uint2*)&A_lds[idx] = make_uint2(lo, hi);
  }
  __syncthreads();

  const int lane = tid & 63, tl = lane & 15, q = lane >> 4;

  f32x4 acc[4][4];
  #pragma unroll
  for (int mi = 0; mi < 4; ++mi)
    #pragma unroll
    for (int ni = 0; ni < 4; ++ni)
      acc[mi][ni] = (f32x4){0.f, 0.f, 0.f, 0.f};

  const bf16x8* wtv = (const bf16x8*)wt;
  const int aswz = (tl & 7) << 3;
  #pragma unroll
  for (int kk = 0; kk < 8; ++kk) {
    bf16x8 a[4], bb[4];
    #pragma unroll
    for (int mi = 0; mi < 4; ++mi)
      a[mi] = *(const bf16x8*)&A_lds[(mi * 16 + tl) * 256 + ((kk * 32 + q * 8) ^ aswz)];
    #pragma unroll
    for (int ni = 0; ni < 4; ++ni)
      bb[ni] = wtv[((((wave << 2) + ni) << 3) + kk) * 64 + lane];
    #pragma unroll
    for (int mi = 0; mi < 4; ++mi)
      #pragma unroll
      for (int ni = 0; ni < 4; ++ni)
        acc[mi][ni] = __builtin_amdgcn_mfma_f32_16x16x32_bf16(a[mi], bb[ni], acc[mi][ni], 0, 0, 0);
  }
  __syncthreads();   // all A_lds reads done -> safe to alias scratch into it

  // ---- epilogue: gelu(h + b1) . w2, reduce over this wave's 64 H cols ----
  float w2v[4], b1v[4];
  #pragma unroll
  for (int ni = 0; ni < 4; ++ni) {
    int h = wave * 64 + ni * 16 + tl;
    w2v[ni] = w2[h];
    b1v[ni] = b1[h];
  }
  #pragma unroll
  for (int mi = 0; mi < 4; ++mi) {
    #pragma unroll
    for (int r = 0; r < 4; ++r) {
      float s = 0.f;
      #pragma unroll
      for (int ni = 0; ni < 4; ++ni) {
        float hv = acc[mi][ni][r] + b1v[ni];
        s += fast_gelu(hv) * w2v[ni];
      }
      #pragma unroll
      for (int m = 1; m < 16; m <<= 1) s += __shfl_xor(s, m, 64);
      if (tl == 0) sc_lds[wave * 64 + mi * 16 + q * 4 + r] = s;
    }
  }
  __syncthreads();

  if (tid < 64) {
    float s = sc_lds[tid] + sc_lds[64 + tid] + sc_lds[128 + tid] + sc_lds[192 + tid] + b2[0];
    float e = __builtin_amdgcn_exp2f(s * -1.44269504088896341f);
    float p = __builtin_amdgcn_rcpf(1.0f + e);
    size_t g = (size_t)tok0 + tid;
    scores[g] = s;
    probs[g] = p;
    p_lds[tid] = p;
    float ent = -(p * logf(p + GEPS) + (1.0f - p) * logf(1.0f - p + GEPS));
    float sp = p, se = ent;
    #pragma unroll
    for (int m = 1; m < 64; m <<= 1) {
      sp += __shfl_xor(sp, m, 64);
      se += __shfl_xor(se, m, 64);
    }
    if (tid == 0) {
      atomicAdd(&sums[b * 2 + 0], sp);
      atomicAdd(&sums[b * 2 + 1], se);
    }
  }
  __syncthreads();

  // ---- y = x * p (L3-hot re-read of x) + bg partial accumulation ----
  float* const yt = y + ((size_t)b * 4097 + n0) * 256 + tid * 4;
  float4 bg = make_float4(0.f, 0.f, 0.f, 0.f);
  #pragma unroll
  for (int i = 0; i < 16; ++i) {
    float4 xv = *(const float4*)(xt + i * 1024);
    float p = p_lds[i * 4 + wave];
    float4 yv = make_float4(xv.x * p, xv.y * p, xv.z * p, xv.w * p);
    *(float4*)(yt + i * 1024) = yv;     // cached store (nt = 2.5x WRITE_SIZE regression, R2)
    float bw = 1.0f - p;
    bg.x += xv.x * bw; bg.y += xv.y * bw; bg.z += xv.z * bw; bg.w += xv.w * bw;
  }
  *(float4*)&bg_lds[tid * 4] = bg;
  __syncthreads();
  {
    float v = bg_lds[tid] + bg_lds[256 + tid] + bg_lds[512 + tid] + bg_lds[768 + tid];
    atomicAdd(&bg_ws[b * 256 + tid], v);
  }
}

__global__ void finalize(const float* __restrict__ bg_ws, const float* __restrict__ sums,
                         const int* __restrict__ kp, float* __restrict__ y,
                         float* __restrict__ aux)
{
  int b = blockIdx.x, c = threadIdx.x;
  float sp = sums[b * 2 + 0];
  float denom = fmaxf(4096.0f - sp, GEPS);
  y[((size_t)b * 4097 + 4096) * 256 + c] = bg_ws[b * 256 + c] / denom;
  if (b == 0 && c == 0) {
    float t = (float)kp[0] / 4096.0f;
    float lr = 0.f, le = 0.f;
    for (int i = 0; i < 32; ++i) {
      float r = sums[i * 2 + 0] / 4096.0f;
      lr += (r - t) * (r - t);
      le += sums[i * 2 + 1];
    }
    aux[0] = lr / 32.0f + 0.01f * (le / (32.0f * 4096.0f));
  }
}

extern "C" void kernel_launch(void* const* d_in, const int* in_sizes, int n_in,
                              void* d_out, int out_size, void* d_ws, size_t ws_size,
                              hipStream_t stream) {
  const float* x  = (const float*)d_in[0];
  const float* W1 = (const float*)d_in[1];
  const float* b1 = (const float*)d_in[2];
  const float* w2 = (const float*)d_in[3];
  const float* b2 = (const float*)d_in[4];
  const int*   kp = (const int*)d_in[5];

  float* y = (float*)d_out;
  const size_t Y_ELEMS = (size_t)32 * 4097 * 256;   // 33,562,624
  float* aux    = y + Y_ELEMS;
  float* scores = aux + 1;
  float* probs  = scores + (size_t)32 * 4096;

  unsigned short* wt = (unsigned short*)d_ws;                 // 128 KB bf16 frag-major W1
  float* bg_ws = (float*)((char*)d_ws + 131072);              // 32x256 fp32
  float* sums  = bg_ws + 32 * 256;                            // 32 x {sum_p, sum_ent}

  hipMemsetAsync(bg_ws, 0, (32 * 256 + 64) * sizeof(float), stream);
  pack_w1<<<32, 256, 0, stream>>>(W1, wt);
  gater_main<<<2048, 256, 0, stream>>>(x, wt, b1, w2, b2, y, scores, probs, bg_ws, sums);
  finalize<<<32, 256, 0, stream>>>(bg_ws, sums, kp, y, aux);
}

// Round 5
// 319.647 us; speedup vs baseline: 2.1041x; 1.0777x over previous
//
#include <hip/hip_runtime.h>
#include <cstdint>

#define GEPS 1e-6f

typedef __attribute__((ext_vector_type(8))) short bf16x8;
typedef __attribute__((ext_vector_type(4))) float f32x4;

__device__ __forceinline__ unsigned short f2bf(float f) {
  unsigned int u = __float_as_uint(f);
  u += 0x7fffu + ((u >> 16) & 1u);
  return (unsigned short)(u >> 16);
}

// Branch-free erf-based exact GELU: A&S 7.1.26, |erf err| <= 1.5e-7.
__device__ __forceinline__ float fast_gelu(float h) {
  float z  = h * 0.70710678118654752f;
  float az = __builtin_fabsf(z);
  float t  = __builtin_amdgcn_rcpf(__builtin_fmaf(0.3275911f, az, 1.0f));
  float poly = t * __builtin_fmaf(t, __builtin_fmaf(t, __builtin_fmaf(t,
               __builtin_fmaf(t, 1.061405429f, -1.453152027f),
               1.421413741f), -0.284496736f), 0.254829592f);
  float e  = __builtin_amdgcn_exp2f(z * z * -1.44269504088896341f);
  float er = __builtin_fmaf(-poly, e, 1.0f);        // erf(|z|)
  er = __builtin_copysignf(er, z);
  float h5 = 0.5f * h;
  return __builtin_fmaf(h5, er, h5);                // 0.5h*(1+erf)
}

// Pack W1 [C=256][H=256] fp32 -> bf16 fragment-major for the B-operand of
// mfma_f32_16x16x32_bf16. Coalesced: thread (h) packs 8 consecutive k into
// one uint4 store.
__global__ void pack_w1(const float* __restrict__ W1, unsigned short* __restrict__ wt) {
  int h  = threadIdx.x;              // 0..255 (H)
  int k8 = blockIdx.x;               // 0..31, group of 8 consecutive k
  int kk = k8 >> 2, q = k8 & 3;
  int h_tile = h >> 4, tl = h & 15;
  unsigned short tmp[8];
  #pragma unroll
  for (int j = 0; j < 8; ++j)
    tmp[j] = f2bf(W1[(k8 * 8 + j) * 256 + h]);
  *(uint4*)&wt[(((h_tile << 3) + kk) << 9) + (q << 7) + (tl << 3)] = *(uint4*)tmp;
}

// 32 tokens/block, x held in registers from staging to the y phase (no re-read).
__global__ __launch_bounds__(256, 4) void gater_main(
    const float* __restrict__ x, const unsigned short* __restrict__ wt,
    const float* __restrict__ b1, const float* __restrict__ w2,
    const float* __restrict__ b2,
    float* __restrict__ y, float* __restrict__ scores, float* __restrict__ probs,
    float* __restrict__ bg_ws, float* __restrict__ sums)
{
  __shared__ short A_lds[32 * 256];              // 16 KB bf16 tile, XOR-swizzled
  float* const sc_lds = (float*)A_lds;           // [4*32]
  float* const p_lds  = (float*)A_lds + 128;     // [32]
  float* const bg_lds = (float*)A_lds + 160;     // [4*256]

  const int tid = threadIdx.x;
  const int wave = tid >> 6;
  const int tok0 = blockIdx.x * 32;     // flat token index (b*N + n)
  const int b = tok0 >> 12;             // N = 4096
  const int n0 = tok0 & 4095;
  const float* xt = x + (size_t)tok0 * 256 + tid * 4;

  // ---- stage x fp32 -> bf16 LDS (swizzled); keep fp32 in registers ----
  float4 xr[8];
  #pragma unroll
  for (int i = 0; i < 8; ++i) {
    int token = i * 4 + wave;                    // wave-uniform token per iter
    xr[i] = *(const float4*)(xt + i * 1024);
    unsigned int lo = (unsigned int)f2bf(xr[i].x) | ((unsigned int)f2bf(xr[i].y) << 16);
    unsigned int hi = (unsigned int)f2bf(xr[i].z) | ((unsigned int)f2bf(xr[i].w) << 16);
    int idx = token * 256 + (((tid & 63) << 2) ^ ((token & 7) << 3));
    *(uint2*)&A_lds[idx] = make_uint2(lo, hi);
  }
  __syncthreads();

  const int lane = tid & 63, tl = lane & 15, q = lane >> 4;

  f32x4 acc[2][4];
  #pragma unroll
  for (int mi = 0; mi < 2; ++mi)
    #pragma unroll
    for (int ni = 0; ni < 4; ++ni)
      acc[mi][ni] = (f32x4){0.f, 0.f, 0.f, 0.f};

  const bf16x8* wtv = (const bf16x8*)wt;
  const int aswz = (tl & 7) << 3;
  #pragma unroll
  for (int kk = 0; kk < 8; ++kk) {
    bf16x8 a[2], bb[4];
    #pragma unroll
    for (int mi = 0; mi < 2; ++mi)
      a[mi] = *(const bf16x8*)&A_lds[(mi * 16 + tl) * 256 + ((kk * 32 + q * 8) ^ aswz)];
    #pragma unroll
    for (int ni = 0; ni < 4; ++ni)
      bb[ni] = wtv[((((wave << 2) + ni) << 3) + kk) * 64 + lane];
    #pragma unroll
    for (int mi = 0; mi < 2; ++mi)
      #pragma unroll
      for (int ni = 0; ni < 4; ++ni)
        acc[mi][ni] = __builtin_amdgcn_mfma_f32_16x16x32_bf16(a[mi], bb[ni], acc[mi][ni], 0, 0, 0);
  }
  __syncthreads();   // A_lds reads done -> scratch may alias it

  // ---- epilogue: gelu(h + b1) . w2, reduce over this wave's 64 H cols ----
  float w2v[4], b1v[4];
  #pragma unroll
  for (int ni = 0; ni < 4; ++ni) {
    int h = wave * 64 + ni * 16 + tl;
    w2v[ni] = w2[h];
    b1v[ni] = b1[h];
  }
  #pragma unroll
  for (int mi = 0; mi < 2; ++mi) {
    #pragma unroll
    for (int r = 0; r < 4; ++r) {
      float s = 0.f;
      #pragma unroll
      for (int ni = 0; ni < 4; ++ni) {
        float hv = acc[mi][ni][r] + b1v[ni];
        s += fast_gelu(hv) * w2v[ni];
      }
      #pragma unroll
      for (int m = 1; m < 16; m <<= 1) s += __shfl_xor(s, m, 64);
      if (tl == 0) sc_lds[wave * 32 + mi * 16 + q * 4 + r] = s;
    }
  }
  __syncthreads();

  if (tid < 32) {
    float s = sc_lds[tid] + sc_lds[32 + tid] + sc_lds[64 + tid] + sc_lds[96 + tid] + b2[0];
    float e = __builtin_amdgcn_exp2f(s * -1.44269504088896341f);
    float p = __builtin_amdgcn_rcpf(1.0f + e);
    size_t g = (size_t)tok0 + tid;
    scores[g] = s;
    probs[g] = p;
    p_lds[tid] = p;
    float ent = -(p * logf(p + GEPS) + (1.0f - p) * logf(1.0f - p + GEPS));
    float sp = p, se = ent;
    #pragma unroll
    for (int m = 1; m < 32; m <<= 1) {         // lanes 0..31 only
      sp += __shfl_xor(sp, m, 64);
      se += __shfl_xor(se, m, 64);
    }
    if (tid == 0) {
      atomicAdd(&sums[b * 2 + 0], sp);
      atomicAdd(&sums[b * 2 + 1], se);
    }
  }
  __syncthreads();

  // ---- y = x_reg * p (stores only, no re-read) + bg partials ----
  float* const yt = y + ((size_t)b * 4097 + n0) * 256 + tid * 4;
  float4 bg = make_float4(0.f, 0.f, 0.f, 0.f);
  #pragma unroll
  for (int i = 0; i < 8; ++i) {
    float p = p_lds[i * 4 + wave];
    float4 xv = xr[i];
    *(float4*)(yt + i * 1024) = make_float4(xv.x * p, xv.y * p, xv.z * p, xv.w * p);
    float bw = 1.0f - p;
    bg.x += xv.x * bw; bg.y += xv.y * bw; bg.z += xv.z * bw; bg.w += xv.w * bw;
  }
  *(float4*)&bg_lds[tid * 4] = bg;
  __syncthreads();
  {
    float v = bg_lds[tid] + bg_lds[256 + tid] + bg_lds[512 + tid] + bg_lds[768 + tid];
    atomicAdd(&bg_ws[b * 256 + tid], v);
  }
}

__global__ void finalize(const float* __restrict__ bg_ws, const float* __restrict__ sums,
                         const int* __restrict__ kp, float* __restrict__ y,
                         float* __restrict__ aux)
{
  int b = blockIdx.x, c = threadIdx.x;
  float sp = sums[b * 2 + 0];
  float denom = fmaxf(4096.0f - sp, GEPS);
  y[((size_t)b * 4097 + 4096) * 256 + c] = bg_ws[b * 256 + c] / denom;
  if (b == 0 && c == 0) {
    float t = (float)kp[0] / 4096.0f;
    float lr = 0.f, le = 0.f;
    for (int i = 0; i < 32; ++i) {
      float r = sums[i * 2 + 0] / 4096.0f;
      lr += (r - t) * (r - t);
      le += sums[i * 2 + 1];
    }
    aux[0] = lr / 32.0f + 0.01f * (le / (32.0f * 4096.0f));
  }
}

extern "C" void kernel_launch(void* const* d_in, const int* in_sizes, int n_in,
                              void* d_out, int out_size, void* d_ws, size_t ws_size,
                              hipStream_t stream) {
  const float* x  = (const float*)d_in[0];
  const float* W1 = (const float*)d_in[1];
  const float* b1 = (const float*)d_in[2];
  const float* w2 = (const float*)d_in[3];
  const float* b2 = (const float*)d_in[4];
  const int*   kp = (const int*)d_in[5];

  float* y = (float*)d_out;
  const size_t Y_ELEMS = (size_t)32 * 4097 * 256;   // 33,562,624
  float* aux    = y + Y_ELEMS;
  float* scores = aux + 1;
  float* probs  = scores + (size_t)32 * 4096;

  unsigned short* wt = (unsigned short*)d_ws;                 // 128 KB bf16 frag-major W1
  float* bg_ws = (float*)((char*)d_ws + 131072);              // 32x256 fp32
  float* sums  = bg_ws + 32 * 256;                            // 32 x {sum_p, sum_ent}

  hipMemsetAsync(bg_ws, 0, (32 * 256 + 64) * sizeof(float), stream);
  pack_w1<<<32, 256, 0, stream>>>(W1, wt);
  gater_main<<<4096, 256, 0, stream>>>(x, wt, b1, w2, b2, y, scores, probs, bg_ws, sums);
  finalize<<<32, 256, 0, stream>>>(bg_ws, sums, kp, y, aux);
}